// Round 1
// baseline (16.836 us; speedup 1.0000x reference)
//
#include <hip/hip_runtime.h>

#define B_SZ 64
#define L_SZ 4096
#define VOCAB 33
#define D_SZ 256

__global__ __launch_bounds__(256) void prot_net_fused(
    const int* __restrict__ X,
    const int* __restrict__ valid_lens,
    const float* __restrict__ emb,
    const float* __restrict__ W1,
    const float* __restrict__ b1,
    const float* __restrict__ W2,
    const float* __restrict__ b2,
    float* __restrict__ out)
{
    __shared__ int   s_cnt[VOCAB];
    __shared__ float s_pool[D_SZ];
    __shared__ float s_h[D_SZ];

    const int b   = blockIdx.x;
    const int tid = threadIdx.x;

    if (tid < VOCAB) s_cnt[tid] = 0;
    __syncthreads();

    // --- Histogram of tokens over valid prefix -------------------------
    const int vl = valid_lens[b];
    const int* xrow = X + b * L_SZ;
    // int4-vectorized read of the token row: 1024 int4, 256 threads -> 4 each
    const int4* xrow4 = reinterpret_cast<const int4*>(xrow);
    #pragma unroll
    for (int i = tid; i < L_SZ / 4; i += 256) {
        int4 t = xrow4[i];
        int l0 = i * 4;
        if (l0 + 0 < vl) atomicAdd(&s_cnt[t.x], 1);
        if (l0 + 1 < vl) atomicAdd(&s_cnt[t.y], 1);
        if (l0 + 2 < vl) atomicAdd(&s_cnt[t.z], 1);
        if (l0 + 3 < vl) atomicAdd(&s_cnt[t.w], 1);
    }
    __syncthreads();

    // --- pooled[d] = sum_v cnt[v] * emb[v, d] --------------------------
    float p = 0.0f;
    #pragma unroll
    for (int v = 0; v < VOCAB; ++v) {
        p += (float)s_cnt[v] * emb[v * D_SZ + tid];
    }
    s_pool[tid] = p;
    __syncthreads();

    // --- h[d] = relu(b1[d] + sum_k pooled[k] * W1[k, d]) ---------------
    float acc1 = b1[tid];
    #pragma unroll 8
    for (int k = 0; k < D_SZ; ++k) {
        acc1 = fmaf(s_pool[k], W1[k * D_SZ + tid], acc1);
    }
    s_h[tid] = fmaxf(acc1, 0.0f);
    __syncthreads();

    // --- out[d] = relu(b2[d] + sum_k h[k] * W2[k, d]) ------------------
    float acc2 = b2[tid];
    #pragma unroll 8
    for (int k = 0; k < D_SZ; ++k) {
        acc2 = fmaf(s_h[k], W2[k * D_SZ + tid], acc2);
    }
    out[b * D_SZ + tid] = fmaxf(acc2, 0.0f);
}

extern "C" void kernel_launch(void* const* d_in, const int* in_sizes, int n_in,
                              void* d_out, int out_size, void* d_ws, size_t ws_size,
                              hipStream_t stream) {
    const int*   X          = (const int*)d_in[0];
    const int*   valid_lens = (const int*)d_in[1];
    const float* emb        = (const float*)d_in[2];
    const float* W1         = (const float*)d_in[3];
    const float* b1         = (const float*)d_in[4];
    const float* W2         = (const float*)d_in[5];
    const float* b2         = (const float*)d_in[6];
    float* out = (float*)d_out;

    prot_net_fused<<<B_SZ, 256, 0, stream>>>(X, valid_lens, emb, W1, b1, W2, b2, out);
}